// Round 7
// baseline (440.297 us; speedup 1.0000x reference)
//
#include <hip/hip_runtime.h>
#include <math.h>

// CILRS fused head — round 7.
// k_emb: builds bf16 emb (perm-ordered) AND computes the whole branch-
//        independent speed path (t1,t2,speed_pred) with its idle MFMA pipe.
// k_main: branch path only (h1 -> h2 -> control head); 35KB LDS -> 4 blk/CU.

#define B_ 65536
#define D_ 512
#define H_ 256

typedef float  f32x4   __attribute__((ext_vector_type(4)));
typedef __bf16 bf16x8  __attribute__((ext_vector_type(8)));
typedef __bf16 bf16x4  __attribute__((ext_vector_type(4)));
typedef float  float4v __attribute__((ext_vector_type(4)));

// ---- ws layout (bytes) ----
#define OFF_COUNTS   0
#define OFF_CURSORS  64
#define OFF_PERM     256        // 65536 ints
#define OFF_PACK     262400     // packed bf16 weights
#define OFF_EMB      3277056    // bf16 [65536][512] perm-ordered
#define WS_FULL      70385920

// packed element offsets (bf16 elements, relative to PK); layout [kc][n][32k]
#define PKO_SW2   0u
#define PKO_BW1   131072u
#define PKO_BW2   917504u
#define PKO_OW1   1310720u
#define PKO_OW2   1441792u

#define PITCH_A 264   // k_main h1 pitch
#define PITCH_T 520   // k_emb emb tile pitch
#define PITCH_S 264   // k_emb t tile pitch

// ---------------- prep ----------------

__global__ void k_zero(int* counts) {
    if (threadIdx.x < 16) counts[threadIdx.x] = 0;
}

__global__ __launch_bounds__(512) void k_hist(const int* __restrict__ command,
                                              int* __restrict__ counts) {
    __shared__ int lh[6];
    int t = threadIdx.x;
    if (t < 6) lh[t] = 0;
    __syncthreads();
    int c = command[blockIdx.x * 512 + t] - 1; c = min(max(c, 0), 5);
    atomicAdd(&lh[c], 1);
    __syncthreads();
    if (t < 6) atomicAdd(&counts[t], lh[t]);
}

__global__ void k_scan(const int* __restrict__ counts, int* __restrict__ cursors) {
    if (threadIdx.x == 0) {
        int s = 0;
        for (int c = 0; c < 6; ++c) { cursors[c] = s; s += counts[c]; }
    }
}

__global__ __launch_bounds__(1024) void k_scatter(const int* __restrict__ command,
                                                  int* __restrict__ cursors,
                                                  int* __restrict__ perm) {
    __shared__ int lh[6], lbase[6];
    int t = threadIdx.x;
    if (t < 6) lh[t] = 0;
    __syncthreads();
    int i = blockIdx.x * 1024 + t;
    int c = command[i] - 1; c = min(max(c, 0), 5);
    int rank = atomicAdd(&lh[c], 1);
    __syncthreads();
    if (t < 6) lbase[t] = atomicAdd(&cursors[t], lh[t]);
    __syncthreads();
    perm[lbase[c] + rank] = i;
}

// W: [C][K][N] fp32 -> PK bf16 [kc][n][32k]
__global__ __launch_bounds__(256) void k_pack(const float* __restrict__ sw2,
                                              const float* __restrict__ bw1,
                                              const float* __restrict__ bw2,
                                              const float* __restrict__ ow1,
                                              const float* __restrict__ ow2,
                                              __bf16* __restrict__ PK) {
    int b = blockIdx.x;
    const float* src; int srcN, colOff; unsigned dstOff; int tt;
    if (b < 64)       { int s = b >> 5;        tt = b & 31;  src = sw2;                          srcN = 512; colOff = s * 256; dstOff = PKO_SW2 + s * 65536u; }
    else if (b < 448) { int i = b - 64;  int c = i >> 6; tt = i & 63; src = bw1 + (size_t)c * 512 * 256; srcN = 256; colOff = 0; dstOff = PKO_BW1 + c * 131072u; }
    else if (b < 640) { int i = b - 448; int c = i >> 5; tt = i & 31; src = bw2 + (size_t)c * 256 * 256; srcN = 256; colOff = 0; dstOff = PKO_BW2 + c * 65536u; }
    else if (b < 704) { tt = b - 640; src = ow1; srcN = 256; colOff = 0; dstOff = PKO_OW1; }
    else              { tt = b - 704; src = ow2; srcN = 256; colOff = 0; dstOff = PKO_OW2; }
    int kc = tt >> 2, nt = tt & 3;
    int k0 = kc * 32, n0 = nt * 64;

    __shared__ __bf16 T[64][34];
    int t = threadIdx.x;
    #pragma unroll
    for (int p = 0; p < 8; ++p) {
        int idx = p * 256 + t;
        int k = idx >> 6, n = idx & 63;
        T[n][k] = (__bf16)src[(size_t)(k0 + k) * srcN + colOff + n0 + n];
    }
    __syncthreads();
    int n = t >> 2, seg = t & 3;
    bf16x8 v;
    #pragma unroll
    for (int j = 0; j < 8; ++j) v[j] = T[n][seg * 8 + j];
    *(bf16x8*)(PK + dstOff + ((unsigned)(kc * 256 + n0 + n) * 32u + seg * 8u)) = v;
}

// ---------------- k_emb: emb build + full speed path ----------------
// 256 thr / 32 rows. Phases: 1) stage embedding->LDS bf16 (8B packed)
// 2) speedMLP MFMA + RMW into tile  3) store tile->embB (perm order)
// 4) t1 = relu(emb@ow1+ob1) -> LDS  5) t2+speed head -> out.

__global__ __launch_bounds__(256, 3) void k_emb(
    const float* __restrict__ embedding, const float* __restrict__ speed,
    const float* __restrict__ sw1, const float* __restrict__ sb1,
    const float* __restrict__ sb2,
    const float* __restrict__ ob1, const float* __restrict__ ob2,
    const float* __restrict__ ow3, const float* __restrict__ ob3,
    const int* __restrict__ perm,
    const __bf16* __restrict__ PK, __bf16* __restrict__ embB,
    float* __restrict__ out)
{
    __shared__ __bf16 s_tile[32 * PITCH_T];   // 33.3 KB
    __shared__ __bf16 s_t[32 * PITCH_S];      // 16.9 KB
    __shared__ int    s_perm[32];
    __shared__ float  s_spd[32];
    __shared__ float  s_sp[32];

    const int tid = threadIdx.x;
    const int q = tid >> 6, lane = tid & 63;
    const int lm = lane & 15, kg = lane >> 4;
    const int R0 = blockIdx.x * 32;

    if (tid < 32) {
        int p = perm[R0 + tid];
        s_perm[tid] = p;
        s_spd[tid] = speed[p];
        s_sp[tid] = 0.f;
    }
    __syncthreads();

    // ---- phase 1: embedding -> LDS bf16 (8B packed stores) ----
    #pragma unroll
    for (int it = 0; it < 16; ++it) {
        int idx = it * 256 + tid;          // 4096 chunks: 32 rows x 128
        int row = idx >> 7, c4 = idx & 127;
        float4v v = *(const float4v*)(embedding + (size_t)s_perm[row] * D_ + c4 * 4);
        bf16x4 pv;
        pv[0] = (__bf16)v[0]; pv[1] = (__bf16)v[1];
        pv[2] = (__bf16)v[2]; pv[3] = (__bf16)v[3];
        *(bf16x4*)(s_tile + row * PITCH_T + c4 * 4) = pv;
    }
    __syncthreads();

    // ---- phase 2: speedMLP MFMA (rank-1 A in regs) + RMW epilogue ----
    {
        const float spd0 = s_spd[lm], spd1 = s_spd[16 + lm];
        const __bf16* bp = PK + PKO_SW2 + (q >> 1) * 65536u
                         + (size_t)((q & 1) * 128 + lm) * 32 + kg * 8;
        f32x4 acc[2][8];
        #pragma unroll
        for (int mt = 0; mt < 2; ++mt)
            #pragma unroll
            for (int ct = 0; ct < 8; ++ct) acc[mt][ct] = f32x4{0.f, 0.f, 0.f, 0.f};

        #pragma unroll 2
        for (int ks = 0; ks < 8; ++ks) {
            const int k0 = ks * 32 + kg * 8;
            float4v w0 = *(const float4v*)(sw1 + k0);
            float4v w1 = *(const float4v*)(sw1 + k0 + 4);
            float4v c0 = *(const float4v*)(sb1 + k0);
            float4v c1 = *(const float4v*)(sb1 + k0 + 4);
            bf16x8 a0, a1;
            #pragma unroll
            for (int j = 0; j < 4; ++j) {
                a0[j]     = (__bf16)fmaxf(spd0 * w0[j] + c0[j], 0.f);
                a0[j + 4] = (__bf16)fmaxf(spd0 * w1[j] + c1[j], 0.f);
                a1[j]     = (__bf16)fmaxf(spd1 * w0[j] + c0[j], 0.f);
                a1[j + 4] = (__bf16)fmaxf(spd1 * w1[j] + c1[j], 0.f);
            }
            #pragma unroll
            for (int ct = 0; ct < 8; ++ct) {
                bf16x8 bv = *(const bf16x8*)(bp + (size_t)ks * 8192 + ct * 512);
                acc[0][ct] = __builtin_amdgcn_mfma_f32_16x16x32_bf16(a0, bv, acc[0][ct], 0, 0, 0);
                acc[1][ct] = __builtin_amdgcn_mfma_f32_16x16x32_bf16(a1, bv, acc[1][ct], 0, 0, 0);
            }
        }
        #pragma unroll
        for (int ct = 0; ct < 8; ++ct) {
            int col = q * 128 + ct * 16 + lm;
            float sb = sb2[col];
            #pragma unroll
            for (int mt = 0; mt < 2; ++mt)
                #pragma unroll
                for (int g = 0; g < 4; ++g) {
                    int row = mt * 16 + kg * 4 + g;
                    int idx = row * PITCH_T + col;
                    float v = acc[mt][ct][g] + sb + (float)s_tile[idx];
                    s_tile[idx] = (__bf16)v;
                }
        }
    }
    __syncthreads();

    // ---- phase 3: store emb tile -> embB (16B chunks, perm order) ----
    #pragma unroll
    for (int it = 0; it < 8; ++it) {
        int idx = it * 256 + tid;          // 2048 chunks: 32 rows x 64
        int row = idx >> 6, c8 = idx & 63;
        *(bf16x8*)(embB + (size_t)(R0 + row) * D_ + c8 * 8) =
            *(const bf16x8*)(s_tile + row * PITCH_T + c8 * 8);
    }

    // ---- phase 4: t1 = relu(emb @ ow1 + ob1); wave q -> cols q*64..+63 ----
    {
        f32x4 ta[2][4];
        #pragma unroll
        for (int mt = 0; mt < 2; ++mt)
            #pragma unroll
            for (int ct = 0; ct < 4; ++ct) ta[mt][ct] = f32x4{0.f, 0.f, 0.f, 0.f};
        const __bf16* a0p = s_tile + lm * PITCH_T + kg * 8;
        const __bf16* a1p = a0p + 16 * PITCH_T;
        const __bf16* bp = PK + PKO_OW1 + (size_t)(q * 64 + lm) * 32 + kg * 8;
        #pragma unroll 2
        for (int ks = 0; ks < 16; ++ks) {
            bf16x8 a0 = *(const bf16x8*)(a0p + ks * 32);
            bf16x8 a1 = *(const bf16x8*)(a1p + ks * 32);
            #pragma unroll
            for (int ct = 0; ct < 4; ++ct) {
                bf16x8 bv = *(const bf16x8*)(bp + (size_t)ks * 8192 + ct * 512);
                ta[0][ct] = __builtin_amdgcn_mfma_f32_16x16x32_bf16(a0, bv, ta[0][ct], 0, 0, 0);
                ta[1][ct] = __builtin_amdgcn_mfma_f32_16x16x32_bf16(a1, bv, ta[1][ct], 0, 0, 0);
            }
        }
        #pragma unroll
        for (int ct = 0; ct < 4; ++ct) {
            int col = q * 64 + ct * 16 + lm;
            float b = ob1[col];
            #pragma unroll
            for (int mt = 0; mt < 2; ++mt)
                #pragma unroll
                for (int g = 0; g < 4; ++g) {
                    int row = mt * 16 + kg * 4 + g;
                    s_t[row * PITCH_S + col] = (__bf16)fmaxf(ta[mt][ct][g] + b, 0.f);
                }
        }
    }
    __syncthreads();

    // ---- phase 5: t2 = relu(t1 @ ow2 + ob2); speed head ----
    {
        f32x4 sa[2][4];
        #pragma unroll
        for (int mt = 0; mt < 2; ++mt)
            #pragma unroll
            for (int ct = 0; ct < 4; ++ct) sa[mt][ct] = f32x4{0.f, 0.f, 0.f, 0.f};
        const __bf16* a0p = s_t + lm * PITCH_S + kg * 8;
        const __bf16* a1p = a0p + 16 * PITCH_S;
        const __bf16* bp = PK + PKO_OW2 + (size_t)(q * 64 + lm) * 32 + kg * 8;
        #pragma unroll 2
        for (int ks = 0; ks < 8; ++ks) {
            bf16x8 a0 = *(const bf16x8*)(a0p + ks * 32);
            bf16x8 a1 = *(const bf16x8*)(a1p + ks * 32);
            #pragma unroll
            for (int ct = 0; ct < 4; ++ct) {
                bf16x8 bv = *(const bf16x8*)(bp + (size_t)ks * 8192 + ct * 512);
                sa[0][ct] = __builtin_amdgcn_mfma_f32_16x16x32_bf16(a0, bv, sa[0][ct], 0, 0, 0);
                sa[1][ct] = __builtin_amdgcn_mfma_f32_16x16x32_bf16(a1, bv, sa[1][ct], 0, 0, 0);
            }
        }
        float sp[2][4];
        #pragma unroll
        for (int mt = 0; mt < 2; ++mt)
            #pragma unroll
            for (int g = 0; g < 4; ++g) sp[mt][g] = 0.f;
        #pragma unroll
        for (int ct = 0; ct < 4; ++ct) {
            int col = q * 64 + ct * 16 + lm;
            float b = ob2[col], wv = ow3[col];
            #pragma unroll
            for (int mt = 0; mt < 2; ++mt)
                #pragma unroll
                for (int g = 0; g < 4; ++g)
                    sp[mt][g] += fmaxf(sa[mt][ct][g] + b, 0.f) * wv;
        }
        #pragma unroll
        for (int mt = 0; mt < 2; ++mt)
            #pragma unroll
            for (int g = 0; g < 4; ++g) {
                float v = sp[mt][g];
                v += __shfl_xor(v, 1); v += __shfl_xor(v, 2);
                v += __shfl_xor(v, 4); v += __shfl_xor(v, 8);
                if (lm == 0) atomicAdd(&s_sp[mt * 16 + kg * 4 + g], v);
            }
    }
    __syncthreads();
    if (tid < 32) out[(size_t)3 * B_ + s_perm[tid]] = s_sp[tid] + ob3[0];
}

// ---------------- k_main: branch path only ----------------
// 256 thr / 64 rows; waves = 2 rowgroups x 2 colhalves; ~35KB LDS -> 4 blk/CU.

__global__ __launch_bounds__(256, 4) void k_main(
    const int* __restrict__ command,
    const float* __restrict__ bb1, const float* __restrict__ bb2,
    const float* __restrict__ bw3, const float* __restrict__ bb3,
    const int* __restrict__ perm, const __bf16* __restrict__ PK,
    const __bf16* __restrict__ embB, float* __restrict__ out)
{
    __shared__ __bf16 s_h1[64 * PITCH_A];
    __shared__ float  s_head[64][3];
    __shared__ int    s_row[64];
    __shared__ int    s_cmd[64];

    const int tid = threadIdx.x;
    const int wave = tid >> 6, lane = tid & 63;
    const int rg = wave >> 1, ch = wave & 1;
    const int lm = lane & 15, kg = lane >> 4, lrow0 = kg * 4;
    const int R0 = blockIdx.x * 64;

    if (tid < 64) {
        int r = perm[R0 + tid];
        s_row[tid] = r;
        int c = command[r] - 1; c = min(max(c, 0), 5);
        s_cmd[tid] = c;
        s_head[tid][0] = 0.f; s_head[tid][1] = 0.f; s_head[tid][2] = 0.f;
    }
    __syncthreads();

    int cc[2][4];
    #pragma unroll
    for (int mt = 0; mt < 2; ++mt)
        #pragma unroll
        for (int g = 0; g < 4; ++g)
            cc[mt][g] = s_cmd[rg * 32 + mt * 16 + lrow0 + g];

    int myc = s_cmd[rg * 32 + (lane & 31)];
    int cmin = myc, cmax = myc;
    #pragma unroll
    for (int d = 1; d < 32; d <<= 1) {
        cmin = min(cmin, __shfl_xor(cmin, d));
        cmax = max(cmax, __shfl_xor(cmax, d));
    }

    const __bf16* aG0 = embB + (size_t)(R0 + rg * 32 + lm) * D_ + kg * 8;
    const __bf16* aG1 = aG0 + (size_t)16 * D_;
    const __bf16* aH0 = s_h1 + (rg * 32 + lm) * PITCH_A + kg * 8;
    const __bf16* aH1 = aH0 + 16 * PITCH_A;
    const size_t bcol = (size_t)(ch * 128 + lm) * 32 + kg * 8;

    // ==== P1: h1 = relu(emb @ bw1[c] + bb1[c]) ====
    for (int c = cmin; c <= cmax; ++c) {
        f32x4 ah[2][8];
        #pragma unroll
        for (int mt = 0; mt < 2; ++mt)
            #pragma unroll
            for (int ct = 0; ct < 8; ++ct) ah[mt][ct] = f32x4{0.f, 0.f, 0.f, 0.f};
        const __bf16* bp = PK + PKO_BW1 + c * 131072u + bcol;
        #pragma unroll 2
        for (int ks = 0; ks < 16; ++ks) {
            bf16x8 a0 = *(const bf16x8*)(aG0 + ks * 32);
            bf16x8 a1 = *(const bf16x8*)(aG1 + ks * 32);
            #pragma unroll
            for (int ct = 0; ct < 8; ++ct) {
                bf16x8 bv = *(const bf16x8*)(bp + (size_t)ks * 8192 + ct * 512);
                ah[0][ct] = __builtin_amdgcn_mfma_f32_16x16x32_bf16(a0, bv, ah[0][ct], 0, 0, 0);
                ah[1][ct] = __builtin_amdgcn_mfma_f32_16x16x32_bf16(a1, bv, ah[1][ct], 0, 0, 0);
            }
        }
        #pragma unroll
        for (int ct = 0; ct < 8; ++ct) {
            int col = ch * 128 + ct * 16 + lm;
            float b = bb1[c * H_ + col];
            #pragma unroll
            for (int mt = 0; mt < 2; ++mt)
                #pragma unroll
                for (int g = 0; g < 4; ++g)
                    if (cc[mt][g] == c) {
                        int row = rg * 32 + mt * 16 + lrow0 + g;
                        s_h1[row * PITCH_A + col] = (__bf16)fmaxf(ah[mt][ct][g] + b, 0.f);
                    }
        }
    }
    __syncthreads();

    // ==== P2: h2 = relu(h1 @ bw2[c] + bb2[c]); control head ====
    for (int c = cmin; c <= cmax; ++c) {
        f32x4 hh[2][8];
        #pragma unroll
        for (int mt = 0; mt < 2; ++mt)
            #pragma unroll
            for (int ct = 0; ct < 8; ++ct) hh[mt][ct] = f32x4{0.f, 0.f, 0.f, 0.f};
        const __bf16* bp = PK + PKO_BW2 + c * 65536u + bcol;
        #pragma unroll 2
        for (int ks = 0; ks < 8; ++ks) {
            bf16x8 h0 = *(const bf16x8*)(aH0 + ks * 32);
            bf16x8 h1v = *(const bf16x8*)(aH1 + ks * 32);
            #pragma unroll
            for (int ct = 0; ct < 8; ++ct) {
                bf16x8 bv = *(const bf16x8*)(bp + (size_t)ks * 8192 + ct * 512);
                hh[0][ct] = __builtin_amdgcn_mfma_f32_16x16x32_bf16(h0, bv, hh[0][ct], 0, 0, 0);
                hh[1][ct] = __builtin_amdgcn_mfma_f32_16x16x32_bf16(h1v, bv, hh[1][ct], 0, 0, 0);
            }
        }
        float ph[2][4][3];
        #pragma unroll
        for (int mt = 0; mt < 2; ++mt)
            #pragma unroll
            for (int g = 0; g < 4; ++g) { ph[mt][g][0] = 0.f; ph[mt][g][1] = 0.f; ph[mt][g][2] = 0.f; }
        #pragma unroll
        for (int ct = 0; ct < 8; ++ct) {
            int col = ch * 128 + ct * 16 + lm;
            float b  = bb2[c * H_ + col];
            float w0 = bw3[(c * H_ + col) * 3 + 0];
            float w1 = bw3[(c * H_ + col) * 3 + 1];
            float w2 = bw3[(c * H_ + col) * 3 + 2];
            #pragma unroll
            for (int mt = 0; mt < 2; ++mt)
                #pragma unroll
                for (int g = 0; g < 4; ++g) {
                    float h = fmaxf(hh[mt][ct][g] + b, 0.f);
                    ph[mt][g][0] += h * w0; ph[mt][g][1] += h * w1; ph[mt][g][2] += h * w2;
                }
        }
        #pragma unroll
        for (int mt = 0; mt < 2; ++mt)
            #pragma unroll
            for (int g = 0; g < 4; ++g)
                #pragma unroll
                for (int o = 0; o < 3; ++o) {
                    float v = ph[mt][g][o];
                    v += __shfl_xor(v, 1); v += __shfl_xor(v, 2);
                    v += __shfl_xor(v, 4); v += __shfl_xor(v, 8);
                    ph[mt][g][o] = v;
                }
        if (lm == 0) {
            #pragma unroll
            for (int mt = 0; mt < 2; ++mt)
                #pragma unroll
                for (int g = 0; g < 4; ++g)
                    if (cc[mt][g] == c) {
                        int row = rg * 32 + mt * 16 + lrow0 + g;
                        atomicAdd(&s_head[row][0], ph[mt][g][0]);
                        atomicAdd(&s_head[row][1], ph[mt][g][1]);
                        atomicAdd(&s_head[row][2], ph[mt][g][2]);
                    }
        }
    }
    __syncthreads();

    if (tid < 64) {
        int ridx = s_row[tid], c = s_cmd[tid];
        #pragma unroll
        for (int o = 0; o < 3; ++o) {
            float x = s_head[tid][o] + bb3[c * 3 + o];
            out[(size_t)ridx * 3 + o] = 1.f / (1.f + __expf(-x));
        }
    }
}

// ---------------- fallback (fp32, no ws) ----------------

__global__ __launch_bounds__(256) void cilrs_slow(
    const float* __restrict__ embedding, const float* __restrict__ speed,
    const int* __restrict__ command,
    const float* __restrict__ sw1, const float* __restrict__ sb1,
    const float* __restrict__ sw2, const float* __restrict__ sb2,
    const float* __restrict__ bw1, const float* __restrict__ bb1,
    const float* __restrict__ bw2, const float* __restrict__ bb2,
    const float* __restrict__ bw3, const float* __restrict__ bb3,
    const float* __restrict__ ow1, const float* __restrict__ ob1,
    const float* __restrict__ ow2, const float* __restrict__ ob2,
    const float* __restrict__ ow3, const float* __restrict__ ob3,
    float* __restrict__ out)
{
    const int row = blockIdx.x;
    const int j   = threadIdx.x;
    __shared__ float sh[H_];
    __shared__ float emb[D_];
    __shared__ float h1[H_];
    __shared__ float h2[H_];
    const float spd = speed[row];
    { float v = spd * sw1[j] + sb1[j]; sh[j] = v > 0.f ? v : 0.f; }
    __syncthreads();
    {
        float a0 = 0.f, a1 = 0.f;
        for (int h = 0; h < H_; ++h) {
            const float s = sh[h];
            a0 += s * sw2[h * D_ + j];
            a1 += s * sw2[h * D_ + j + 256];
        }
        emb[j]       = embedding[(size_t)row * D_ + j]       + a0 + sb2[j];
        emb[j + 256] = embedding[(size_t)row * D_ + j + 256] + a1 + sb2[j + 256];
    }
    __syncthreads();
    const int n = command[row] - 1;
    {
        const float* wp = bw1 + (size_t)n * D_ * H_;
        float a = 0.f;
        for (int d = 0; d < D_; ++d) a += emb[d] * wp[d * H_ + j];
        a += bb1[n * H_ + j];
        h1[j] = a > 0.f ? a : 0.f;
    }
    __syncthreads();
    {
        const float* wp = bw2 + (size_t)n * H_ * H_;
        float a = 0.f;
        for (int h = 0; h < H_; ++h) a += h1[h] * wp[h * H_ + j];
        a += bb2[n * H_ + j];
        h2[j] = a > 0.f ? a : 0.f;
    }
    __syncthreads();
    {
        float a = 0.f;
        for (int d = 0; d < D_; ++d) a += emb[d] * ow1[d * H_ + j];
        a += ob1[j];
        sh[j] = a > 0.f ? a : 0.f;
    }
    __syncthreads();
    {
        float a = 0.f;
        for (int h = 0; h < H_; ++h) a += sh[h] * ow2[h * H_ + j];
        a += ob2[j];
        h1[j] = a > 0.f ? a : 0.f;
    }
    __syncthreads();
    if (j < 3) {
        const float* wp = bw3 + (size_t)n * H_ * 3;
        float a = 0.f;
        for (int h = 0; h < H_; ++h) a += h2[h] * wp[h * 3 + j];
        a += bb3[n * 3 + j];
        out[(size_t)row * 3 + j] = 1.f / (1.f + expf(-a));
    } else if (j == 3) {
        float a = 0.f;
        for (int h = 0; h < H_; ++h) a += h1[h] * ow3[h];
        a += ob3[0];
        out[(size_t)B_ * 3 + row] = a;
    }
}

// ---------------- launch ----------------

extern "C" void kernel_launch(void* const* d_in, const int* in_sizes, int n_in,
                              void* d_out, int out_size, void* d_ws, size_t ws_size,
                              hipStream_t stream) {
    const float* embedding = (const float*)d_in[0];
    const float* speed     = (const float*)d_in[1];
    const int*   command   = (const int*)  d_in[2];
    const float* sw1 = (const float*)d_in[3];
    const float* sb1 = (const float*)d_in[4];
    const float* sw2 = (const float*)d_in[5];
    const float* sb2 = (const float*)d_in[6];
    const float* bw1 = (const float*)d_in[7];
    const float* bb1 = (const float*)d_in[8];
    const float* bw2 = (const float*)d_in[9];
    const float* bb2 = (const float*)d_in[10];
    const float* bw3 = (const float*)d_in[11];
    const float* bb3 = (const float*)d_in[12];
    const float* ow1 = (const float*)d_in[13];
    const float* ob1 = (const float*)d_in[14];
    const float* ow2 = (const float*)d_in[15];
    const float* ob2 = (const float*)d_in[16];
    const float* ow3 = (const float*)d_in[17];
    const float* ob3 = (const float*)d_in[18];
    float* out = (float*)d_out;

    if (ws_size < (size_t)WS_FULL) {
        cilrs_slow<<<B_, 256, 0, stream>>>(embedding, speed, command,
                                           sw1, sb1, sw2, sb2,
                                           bw1, bb1, bw2, bb2, bw3, bb3,
                                           ow1, ob1, ow2, ob2, ow3, ob3, out);
        return;
    }

    char* ws = (char*)d_ws;
    int*    counts  = (int*)   (ws + OFF_COUNTS);
    int*    cursors = (int*)   (ws + OFF_CURSORS);
    int*    perm    = (int*)   (ws + OFF_PERM);
    __bf16* PK      = (__bf16*)(ws + OFF_PACK);
    __bf16* embB    = (__bf16*)(ws + OFF_EMB);

    k_zero<<<1, 64, 0, stream>>>(counts);
    k_hist<<<B_ / 512, 512, 0, stream>>>(command, counts);
    k_scan<<<1, 64, 0, stream>>>(counts, cursors);
    k_scatter<<<B_ / 1024, 1024, 0, stream>>>(command, cursors, perm);
    k_pack<<<736, 256, 0, stream>>>(sw2, bw1, bw2, ow1, ow2, PK);
    k_emb<<<B_ / 32, 256, 0, stream>>>(embedding, speed, sw1, sb1, sb2,
                                       ob1, ob2, ow3, ob3, perm, PK, embB, out);
    k_main<<<B_ / 64, 256, 0, stream>>>(command,
                                        bb1, bb2, bw3, bb3,
                                        perm, PK, embB, out);
}

// Round 8
// 390.909 us; speedup vs baseline: 1.1263x; 1.1263x over previous
//
#include <hip/hip_runtime.h>
#include <math.h>

// CILRS fused head — round 8.  THREE dispatches total:
//  1) k_countscan: 1-block hist+scan -> cursors
//  2) k_prepB:     scatter (blocks 0..255) + weight pack (blocks 256..991)
//  3) k_fused:     per 32-row tile: stage emb->LDS, transposed speedMLP
//                  (vectorized LDS RMW), h1->h2+control, t1->t2+speed.
// No embB intermediate; emb lives only in LDS.

#define B_ 65536
#define D_ 512
#define H_ 256

typedef float  f32x4   __attribute__((ext_vector_type(4)));
typedef __bf16 bf16x8  __attribute__((ext_vector_type(8)));
typedef __bf16 bf16x4  __attribute__((ext_vector_type(4)));
typedef float  float4v __attribute__((ext_vector_type(4)));

// ---- ws layout (bytes) ----
#define OFF_CURSORS  64
#define OFF_PERM     256        // 65536 ints
#define OFF_PACK     262400     // packed bf16 weights (3,014,656 B)
#define WS_NEEDED    3277056

// packed element offsets (bf16 elements, relative to PK); layout [kc][n][32k]
#define PKO_SW2   0u
#define PKO_BW1   131072u
#define PKO_BW2   917504u
#define PKO_OW1   1310720u
#define PKO_OW2   1441792u

#define PITCH_E 520   // emb tile pitch (bf16)
#define PITCH_H 264   // h/t buffer pitch (bf16)

// ---------------- prep 1: one-block hist + scan ----------------

__global__ __launch_bounds__(1024) void k_countscan(const int* __restrict__ command,
                                                    int* __restrict__ cursors) {
    __shared__ int red[6][1024];
    int t = threadIdx.x;
    int c0 = 0, c1 = 0, c2 = 0, c3 = 0, c4 = 0, c5 = 0;
    for (int i = t; i < B_; i += 1024) {
        int c = command[i] - 1; c = min(max(c, 0), 5);
        c0 += (c == 0); c1 += (c == 1); c2 += (c == 2);
        c3 += (c == 3); c4 += (c == 4); c5 += (c == 5);
    }
    red[0][t] = c0; red[1][t] = c1; red[2][t] = c2;
    red[3][t] = c3; red[4][t] = c4; red[5][t] = c5;
    __syncthreads();
    for (int s = 512; s > 0; s >>= 1) {
        if (t < s) {
            #pragma unroll
            for (int c = 0; c < 6; ++c) red[c][t] += red[c][t + s];
        }
        __syncthreads();
    }
    if (t == 0) {
        int sum = 0;
        #pragma unroll
        for (int c = 0; c < 6; ++c) { cursors[c] = sum; sum += red[c][0]; }
    }
}

// ---------------- prep 2: scatter + pack fused ----------------

__global__ __launch_bounds__(256) void k_prepB(const int* __restrict__ command,
                                               int* __restrict__ cursors,
                                               int* __restrict__ perm,
                                               const float* __restrict__ sw2,
                                               const float* __restrict__ bw1,
                                               const float* __restrict__ bw2,
                                               const float* __restrict__ ow1,
                                               const float* __restrict__ ow2,
                                               __bf16* __restrict__ PK) {
    int t = threadIdx.x;
    if (blockIdx.x < 256) {
        // ---- scatter ----
        __shared__ int lh[6], lbase[6];
        if (t < 6) lh[t] = 0;
        __syncthreads();
        int i = blockIdx.x * 256 + t;
        int c = command[i] - 1; c = min(max(c, 0), 5);
        int rank = atomicAdd(&lh[c], 1);
        __syncthreads();
        if (t < 6) lbase[t] = atomicAdd(&cursors[t], lh[t]);
        __syncthreads();
        perm[lbase[c] + rank] = i;
        return;
    }
    // ---- pack: W [C][K][N] fp32 -> PK bf16 [kc][n][32k] ----
    int b = blockIdx.x - 256;
    const float* src; int srcN, colOff; unsigned dstOff; int tt;
    if (b < 64)       { int s = b >> 5;        tt = b & 31;  src = sw2;                          srcN = 512; colOff = s * 256; dstOff = PKO_SW2 + s * 65536u; }
    else if (b < 448) { int i = b - 64;  int c = i >> 6; tt = i & 63; src = bw1 + (size_t)c * 512 * 256; srcN = 256; colOff = 0; dstOff = PKO_BW1 + c * 131072u; }
    else if (b < 640) { int i = b - 448; int c = i >> 5; tt = i & 31; src = bw2 + (size_t)c * 256 * 256; srcN = 256; colOff = 0; dstOff = PKO_BW2 + c * 65536u; }
    else if (b < 704) { tt = b - 640; src = ow1; srcN = 256; colOff = 0; dstOff = PKO_OW1; }
    else              { tt = b - 704; src = ow2; srcN = 256; colOff = 0; dstOff = PKO_OW2; }
    int kc = tt >> 2, nt = tt & 3;
    int k0 = kc * 32, n0 = nt * 64;

    __shared__ __bf16 T[64][34];
    #pragma unroll
    for (int p = 0; p < 8; ++p) {
        int idx = p * 256 + t;
        int k = idx >> 6, n = idx & 63;
        T[n][k] = (__bf16)src[(size_t)(k0 + k) * srcN + colOff + n0 + n];
    }
    __syncthreads();
    int n = t >> 2, seg = t & 3;
    bf16x8 v;
    #pragma unroll
    for (int j = 0; j < 8; ++j) v[j] = T[n][seg * 8 + j];
    *(bf16x8*)(PK + dstOff + ((unsigned)(kc * 256 + n0 + n) * 32u + seg * 8u)) = v;
}

// ---------------- fused main: 32 rows/block, everything in LDS ----------------

__global__ __launch_bounds__(256, 3) void k_fused(
    const float* __restrict__ embedding, const float* __restrict__ speed,
    const int*   __restrict__ command,
    const float* __restrict__ sw1, const float* __restrict__ sb1,
    const float* __restrict__ sb2,
    const float* __restrict__ bb1, const float* __restrict__ bb2,
    const float* __restrict__ bw3, const float* __restrict__ bb3,
    const float* __restrict__ ob1, const float* __restrict__ ob2,
    const float* __restrict__ ow3, const float* __restrict__ ob3,
    const int* __restrict__ perm, const __bf16* __restrict__ PK,
    float* __restrict__ out)
{
    __shared__ __bf16 s_emb[32 * PITCH_E];   // 33.3 KB
    __shared__ __bf16 s_h[32 * PITCH_H];     // 16.9 KB
    __shared__ float  s_head[32][4];
    __shared__ int    s_row[32];
    __shared__ int    s_cmd[32];
    __shared__ float  s_spd[32];

    const int tid = threadIdx.x;
    const int w = tid >> 6, lane = tid & 63;
    const int lm = lane & 15, kg = lane >> 4;
    const int R0 = blockIdx.x * 32;

    if (tid < 32) {
        int r = perm[R0 + tid];
        s_row[tid] = r;
        int c = command[r] - 1; c = min(max(c, 0), 5);
        s_cmd[tid] = c;
        s_spd[tid] = speed[r];
        s_head[tid][0] = 0.f; s_head[tid][1] = 0.f; s_head[tid][2] = 0.f; s_head[tid][3] = 0.f;
    }
    __syncthreads();

    // ---- stage embedding -> LDS bf16 ----
    #pragma unroll
    for (int it = 0; it < 16; ++it) {
        int idx = it * 256 + tid;          // 4096 chunks: 32 rows x 128
        int row = idx >> 7, c4 = idx & 127;
        float4v v = *(const float4v*)(embedding + (size_t)s_row[row] * D_ + c4 * 4);
        bf16x4 pv;
        pv[0] = (__bf16)v[0]; pv[1] = (__bf16)v[1];
        pv[2] = (__bf16)v[2]; pv[3] = (__bf16)v[3];
        *(bf16x4*)(s_emb + row * PITCH_E + c4 * 4) = pv;
    }
    __syncthreads();

    int cc[2][4];
    #pragma unroll
    for (int mt = 0; mt < 2; ++mt)
        #pragma unroll
        for (int g = 0; g < 4; ++g)
            cc[mt][g] = s_cmd[mt * 16 + kg * 4 + g];

    int myc = s_cmd[lane & 31];
    int cmin = myc, cmax = myc;
    #pragma unroll
    for (int d = 1; d < 32; d <<= 1) {
        cmin = min(cmin, __shfl_xor(cmin, d));
        cmax = max(cmax, __shfl_xor(cmax, d));
    }

    // ---- transposed speedMLP: deltaT = sw2T @ shT; vectorized LDS RMW ----
    // wave w owns emb cols w*128..+128 (8 M-tiles); N = 32 rows (2 N-tiles)
    {
        const float spd0 = s_spd[lm], spd1 = s_spd[16 + lm];
        const unsigned slice = (unsigned)(w >> 1) * 65536u;
        const int mbase = (w & 1) * 128;
        f32x4 dacc[8][2];
        #pragma unroll
        for (int mt = 0; mt < 8; ++mt) {
            dacc[mt][0] = f32x4{0.f, 0.f, 0.f, 0.f};
            dacc[mt][1] = f32x4{0.f, 0.f, 0.f, 0.f};
        }
        #pragma unroll 2
        for (int ks = 0; ks < 8; ++ks) {
            const int k0 = ks * 32 + kg * 8;
            float4v w0 = *(const float4v*)(sw1 + k0);
            float4v w1 = *(const float4v*)(sw1 + k0 + 4);
            float4v c0 = *(const float4v*)(sb1 + k0);
            float4v c1 = *(const float4v*)(sb1 + k0 + 4);
            bf16x8 b0, b1;
            #pragma unroll
            for (int j = 0; j < 4; ++j) {
                b0[j]     = (__bf16)fmaxf(spd0 * w0[j] + c0[j], 0.f);
                b0[j + 4] = (__bf16)fmaxf(spd0 * w1[j] + c1[j], 0.f);
                b1[j]     = (__bf16)fmaxf(spd1 * w0[j] + c0[j], 0.f);
                b1[j + 4] = (__bf16)fmaxf(spd1 * w1[j] + c1[j], 0.f);
            }
            const __bf16* ap = PK + PKO_SW2 + slice + (size_t)ks * 8192
                             + (size_t)(mbase + lm) * 32 + kg * 8;
            #pragma unroll
            for (int mt = 0; mt < 8; ++mt) {
                bf16x8 av = *(const bf16x8*)(ap + mt * 512);
                dacc[mt][0] = __builtin_amdgcn_mfma_f32_16x16x32_bf16(av, b0, dacc[mt][0], 0, 0, 0);
                dacc[mt][1] = __builtin_amdgcn_mfma_f32_16x16x32_bf16(av, b1, dacc[mt][1], 0, 0, 0);
            }
        }
        // epilogue: lane holds 4 consecutive emb-cols for rows nt*16+lm
        #pragma unroll
        for (int mt = 0; mt < 8; ++mt) {
            int colb = w * 128 + mt * 16 + kg * 4;
            float4v sbv = *(const float4v*)(sb2 + colb);
            #pragma unroll
            for (int nt = 0; nt < 2; ++nt) {
                int row = nt * 16 + lm;
                bf16x4* p = (bf16x4*)(s_emb + row * PITCH_E + colb);
                bf16x4 old = *p;
                bf16x4 nv;
                #pragma unroll
                for (int g = 0; g < 4; ++g)
                    nv[g] = (__bf16)(dacc[mt][nt][g] + sbv[g] + (float)old[g]);
                *p = nv;
            }
        }
    }
    __syncthreads();

    const __bf16* aE0 = s_emb + lm * PITCH_E + kg * 8;
    const __bf16* aE1 = aE0 + 16 * PITCH_E;
    const __bf16* aH0 = s_h + lm * PITCH_H + kg * 8;
    const __bf16* aH1 = aH0 + 16 * PITCH_H;
    const size_t bcol = (size_t)(w * 64 + lm) * 32 + kg * 8;

    // ---- h1 = relu(emb @ bw1[c] + bb1[c]) ----
    for (int c = cmin; c <= cmax; ++c) {
        f32x4 ah[2][4];
        #pragma unroll
        for (int mt = 0; mt < 2; ++mt)
            #pragma unroll
            for (int ct = 0; ct < 4; ++ct) ah[mt][ct] = f32x4{0.f, 0.f, 0.f, 0.f};
        const __bf16* bp = PK + PKO_BW1 + c * 131072u + bcol;
        #pragma unroll 2
        for (int ks = 0; ks < 16; ++ks) {
            bf16x8 a0 = *(const bf16x8*)(aE0 + ks * 32);
            bf16x8 a1 = *(const bf16x8*)(aE1 + ks * 32);
            #pragma unroll
            for (int ct = 0; ct < 4; ++ct) {
                bf16x8 bv = *(const bf16x8*)(bp + (size_t)ks * 8192 + ct * 512);
                ah[0][ct] = __builtin_amdgcn_mfma_f32_16x16x32_bf16(a0, bv, ah[0][ct], 0, 0, 0);
                ah[1][ct] = __builtin_amdgcn_mfma_f32_16x16x32_bf16(a1, bv, ah[1][ct], 0, 0, 0);
            }
        }
        #pragma unroll
        for (int ct = 0; ct < 4; ++ct) {
            int col = w * 64 + ct * 16 + lm;
            float b = bb1[c * H_ + col];
            #pragma unroll
            for (int mt = 0; mt < 2; ++mt)
                #pragma unroll
                for (int g = 0; g < 4; ++g)
                    if (cc[mt][g] == c) {
                        int row = mt * 16 + kg * 4 + g;
                        s_h[row * PITCH_H + col] = (__bf16)fmaxf(ah[mt][ct][g] + b, 0.f);
                    }
        }
    }
    __syncthreads();

    // ---- h2 = relu(h1 @ bw2[c] + bb2[c]); control head in-register ----
    for (int c = cmin; c <= cmax; ++c) {
        f32x4 hh[2][4];
        #pragma unroll
        for (int mt = 0; mt < 2; ++mt)
            #pragma unroll
            for (int ct = 0; ct < 4; ++ct) hh[mt][ct] = f32x4{0.f, 0.f, 0.f, 0.f};
        const __bf16* bp = PK + PKO_BW2 + c * 65536u + bcol;
        #pragma unroll 2
        for (int ks = 0; ks < 8; ++ks) {
            bf16x8 a0 = *(const bf16x8*)(aH0 + ks * 32);
            bf16x8 a1 = *(const bf16x8*)(aH1 + ks * 32);
            #pragma unroll
            for (int ct = 0; ct < 4; ++ct) {
                bf16x8 bv = *(const bf16x8*)(bp + (size_t)ks * 8192 + ct * 512);
                hh[0][ct] = __builtin_amdgcn_mfma_f32_16x16x32_bf16(a0, bv, hh[0][ct], 0, 0, 0);
                hh[1][ct] = __builtin_amdgcn_mfma_f32_16x16x32_bf16(a1, bv, hh[1][ct], 0, 0, 0);
            }
        }
        float ph[2][4][3];
        #pragma unroll
        for (int mt = 0; mt < 2; ++mt)
            #pragma unroll
            for (int g = 0; g < 4; ++g) { ph[mt][g][0] = 0.f; ph[mt][g][1] = 0.f; ph[mt][g][2] = 0.f; }
        #pragma unroll
        for (int ct = 0; ct < 4; ++ct) {
            int col = w * 64 + ct * 16 + lm;
            float b  = bb2[c * H_ + col];
            float w0 = bw3[(c * H_ + col) * 3 + 0];
            float w1 = bw3[(c * H_ + col) * 3 + 1];
            float w2 = bw3[(c * H_ + col) * 3 + 2];
            #pragma unroll
            for (int mt = 0; mt < 2; ++mt)
                #pragma unroll
                for (int g = 0; g < 4; ++g) {
                    float h = fmaxf(hh[mt][ct][g] + b, 0.f);
                    ph[mt][g][0] += h * w0; ph[mt][g][1] += h * w1; ph[mt][g][2] += h * w2;
                }
        }
        #pragma unroll
        for (int mt = 0; mt < 2; ++mt)
            #pragma unroll
            for (int g = 0; g < 4; ++g)
                #pragma unroll
                for (int o = 0; o < 3; ++o) {
                    float v = ph[mt][g][o];
                    v += __shfl_xor(v, 1); v += __shfl_xor(v, 2);
                    v += __shfl_xor(v, 4); v += __shfl_xor(v, 8);
                    ph[mt][g][o] = v;
                }
        if (lm == 0) {
            #pragma unroll
            for (int mt = 0; mt < 2; ++mt)
                #pragma unroll
                for (int g = 0; g < 4; ++g)
                    if (cc[mt][g] == c) {
                        int row = mt * 16 + kg * 4 + g;
                        atomicAdd(&s_head[row][0], ph[mt][g][0]);
                        atomicAdd(&s_head[row][1], ph[mt][g][1]);
                        atomicAdd(&s_head[row][2], ph[mt][g][2]);
                    }
        }
    }
    __syncthreads();   // s_h about to be overwritten by t1

    // ---- t1 = relu(emb @ ow1 + ob1) -> s_h ----
    {
        f32x4 ta[2][4];
        #pragma unroll
        for (int mt = 0; mt < 2; ++mt)
            #pragma unroll
            for (int ct = 0; ct < 4; ++ct) ta[mt][ct] = f32x4{0.f, 0.f, 0.f, 0.f};
        const __bf16* bp = PK + PKO_OW1 + bcol;
        #pragma unroll 2
        for (int ks = 0; ks < 16; ++ks) {
            bf16x8 a0 = *(const bf16x8*)(aE0 + ks * 32);
            bf16x8 a1 = *(const bf16x8*)(aE1 + ks * 32);
            #pragma unroll
            for (int ct = 0; ct < 4; ++ct) {
                bf16x8 bv = *(const bf16x8*)(bp + (size_t)ks * 8192 + ct * 512);
                ta[0][ct] = __builtin_amdgcn_mfma_f32_16x16x32_bf16(a0, bv, ta[0][ct], 0, 0, 0);
                ta[1][ct] = __builtin_amdgcn_mfma_f32_16x16x32_bf16(a1, bv, ta[1][ct], 0, 0, 0);
            }
        }
        #pragma unroll
        for (int ct = 0; ct < 4; ++ct) {
            int col = w * 64 + ct * 16 + lm;
            float b = ob1[col];
            #pragma unroll
            for (int mt = 0; mt < 2; ++mt)
                #pragma unroll
                for (int g = 0; g < 4; ++g) {
                    int row = mt * 16 + kg * 4 + g;
                    s_h[row * PITCH_H + col] = (__bf16)fmaxf(ta[mt][ct][g] + b, 0.f);
                }
        }
    }
    __syncthreads();

    // ---- t2 = relu(t1 @ ow2 + ob2); speed head ----
    {
        f32x4 sa[2][4];
        #pragma unroll
        for (int mt = 0; mt < 2; ++mt)
            #pragma unroll
            for (int ct = 0; ct < 4; ++ct) sa[mt][ct] = f32x4{0.f, 0.f, 0.f, 0.f};
        const __bf16* bp = PK + PKO_OW2 + bcol;
        #pragma unroll 2
        for (int ks = 0; ks < 8; ++ks) {
            bf16x8 a0 = *(const bf16x8*)(aH0 + ks * 32);
            bf16x8 a1 = *(const bf16x8*)(aH1 + ks * 32);
            #pragma unroll
            for (int ct = 0; ct < 4; ++ct) {
                bf16x8 bv = *(const bf16x8*)(bp + (size_t)ks * 8192 + ct * 512);
                sa[0][ct] = __builtin_amdgcn_mfma_f32_16x16x32_bf16(a0, bv, sa[0][ct], 0, 0, 0);
                sa[1][ct] = __builtin_amdgcn_mfma_f32_16x16x32_bf16(a1, bv, sa[1][ct], 0, 0, 0);
            }
        }
        float sp[2][4];
        #pragma unroll
        for (int mt = 0; mt < 2; ++mt)
            #pragma unroll
            for (int g = 0; g < 4; ++g) sp[mt][g] = 0.f;
        #pragma unroll
        for (int ct = 0; ct < 4; ++ct) {
            int col = w * 64 + ct * 16 + lm;
            float b = ob2[col], wv = ow3[col];
            #pragma unroll
            for (int mt = 0; mt < 2; ++mt)
                #pragma unroll
                for (int g = 0; g < 4; ++g)
                    sp[mt][g] += fmaxf(sa[mt][ct][g] + b, 0.f) * wv;
        }
        #pragma unroll
        for (int mt = 0; mt < 2; ++mt)
            #pragma unroll
            for (int g = 0; g < 4; ++g) {
                float v = sp[mt][g];
                v += __shfl_xor(v, 1); v += __shfl_xor(v, 2);
                v += __shfl_xor(v, 4); v += __shfl_xor(v, 8);
                if (lm == 0) atomicAdd(&s_head[mt * 16 + kg * 4 + g][3], v);
            }
    }
    __syncthreads();

    if (tid < 32) {
        int r = s_row[tid], c = s_cmd[tid];
        #pragma unroll
        for (int o = 0; o < 3; ++o) {
            float x = s_head[tid][o] + bb3[c * 3 + o];
            out[(size_t)r * 3 + o] = 1.f / (1.f + __expf(-x));
        }
        out[(size_t)3 * B_ + r] = s_head[tid][3] + ob3[0];
    }
}

// ---------------- fallback (fp32, no ws) ----------------

__global__ __launch_bounds__(256) void cilrs_slow(
    const float* __restrict__ embedding, const float* __restrict__ speed,
    const int* __restrict__ command,
    const float* __restrict__ sw1, const float* __restrict__ sb1,
    const float* __restrict__ sw2, const float* __restrict__ sb2,
    const float* __restrict__ bw1, const float* __restrict__ bb1,
    const float* __restrict__ bw2, const float* __restrict__ bb2,
    const float* __restrict__ bw3, const float* __restrict__ bb3,
    const float* __restrict__ ow1, const float* __restrict__ ob1,
    const float* __restrict__ ow2, const float* __restrict__ ob2,
    const float* __restrict__ ow3, const float* __restrict__ ob3,
    float* __restrict__ out)
{
    const int row = blockIdx.x;
    const int j   = threadIdx.x;
    __shared__ float sh[H_];
    __shared__ float emb[D_];
    __shared__ float h1[H_];
    __shared__ float h2[H_];
    const float spd = speed[row];
    { float v = spd * sw1[j] + sb1[j]; sh[j] = v > 0.f ? v : 0.f; }
    __syncthreads();
    {
        float a0 = 0.f, a1 = 0.f;
        for (int h = 0; h < H_; ++h) {
            const float s = sh[h];
            a0 += s * sw2[h * D_ + j];
            a1 += s * sw2[h * D_ + j + 256];
        }
        emb[j]       = embedding[(size_t)row * D_ + j]       + a0 + sb2[j];
        emb[j + 256] = embedding[(size_t)row * D_ + j + 256] + a1 + sb2[j + 256];
    }
    __syncthreads();
    const int n = command[row] - 1;
    {
        const float* wp = bw1 + (size_t)n * D_ * H_;
        float a = 0.f;
        for (int d = 0; d < D_; ++d) a += emb[d] * wp[d * H_ + j];
        a += bb1[n * H_ + j];
        h1[j] = a > 0.f ? a : 0.f;
    }
    __syncthreads();
    {
        const float* wp = bw2 + (size_t)n * H_ * H_;
        float a = 0.f;
        for (int h = 0; h < H_; ++h) a += h1[h] * wp[h * H_ + j];
        a += bb2[n * H_ + j];
        h2[j] = a > 0.f ? a : 0.f;
    }
    __syncthreads();
    {
        float a = 0.f;
        for (int d = 0; d < D_; ++d) a += emb[d] * ow1[d * H_ + j];
        a += ob1[j];
        sh[j] = a > 0.f ? a : 0.f;
    }
    __syncthreads();
    {
        float a = 0.f;
        for (int h = 0; h < H_; ++h) a += sh[h] * ow2[h * H_ + j];
        a += ob2[j];
        h1[j] = a > 0.f ? a : 0.f;
    }
    __syncthreads();
    if (j < 3) {
        const float* wp = bw3 + (size_t)n * H_ * 3;
        float a = 0.f;
        for (int h = 0; h < H_; ++h) a += h2[h] * wp[h * 3 + j];
        a += bb3[n * 3 + j];
        out[(size_t)row * 3 + j] = 1.f / (1.f + expf(-a));
    } else if (j == 3) {
        float a = 0.f;
        for (int h = 0; h < H_; ++h) a += h1[h] * ow3[h];
        a += ob3[0];
        out[(size_t)B_ * 3 + row] = a;
    }
}

// ---------------- launch ----------------

extern "C" void kernel_launch(void* const* d_in, const int* in_sizes, int n_in,
                              void* d_out, int out_size, void* d_ws, size_t ws_size,
                              hipStream_t stream) {
    const float* embedding = (const float*)d_in[0];
    const float* speed     = (const float*)d_in[1];
    const int*   command   = (const int*)  d_in[2];
    const float* sw1 = (const float*)d_in[3];
    const float* sb1 = (const float*)d_in[4];
    const float* sw2 = (const float*)d_in[5];
    const float* sb2 = (const float*)d_in[6];
    const float* bw1 = (const float*)d_in[7];
    const float* bb1 = (const float*)d_in[8];
    const float* bw2 = (const float*)d_in[9];
    const float* bb2 = (const float*)d_in[10];
    const float* bw3 = (const float*)d_in[11];
    const float* bb3 = (const float*)d_in[12];
    const float* ow1 = (const float*)d_in[13];
    const float* ob1 = (const float*)d_in[14];
    const float* ow2 = (const float*)d_in[15];
    const float* ob2 = (const float*)d_in[16];
    const float* ow3 = (const float*)d_in[17];
    const float* ob3 = (const float*)d_in[18];
    float* out = (float*)d_out;

    if (ws_size < (size_t)WS_NEEDED) {
        cilrs_slow<<<B_, 256, 0, stream>>>(embedding, speed, command,
                                           sw1, sb1, sw2, sb2,
                                           bw1, bb1, bw2, bb2, bw3, bb3,
                                           ow1, ob1, ow2, ob2, ow3, ob3, out);
        return;
    }

    char* ws = (char*)d_ws;
    int*    cursors = (int*)   (ws + OFF_CURSORS);
    int*    perm    = (int*)   (ws + OFF_PERM);
    __bf16* PK      = (__bf16*)(ws + OFF_PACK);

    k_countscan<<<1, 1024, 0, stream>>>(command, cursors);
    k_prepB<<<992, 256, 0, stream>>>(command, cursors, perm,
                                     sw2, bw1, bw2, ow1, ow2, PK);
    k_fused<<<B_ / 32, 256, 0, stream>>>(embedding, speed, command,
                                         sw1, sb1, sb2,
                                         bb1, bb2, bw3, bb3,
                                         ob1, ob2, ow3, ob3,
                                         perm, PK, out);
}